// Round 6
// baseline (1037.662 us; speedup 1.0000x reference)
//
#include <hip/hip_runtime.h>
#include <math.h>

// ---------------------------------------------------------------------------
// MeshCaster on MI355X — round 6.
// r5 (588us) regressed vs r4 (521us) purely from scratch spill in the batched
// gather (WRITE_SIZE 53->258MB). r6 = r5 structure (BM=64, 8 waves, 2
// blocks/CU, halved L2 weight traffic) with r4's proven pair-pipelined
// gather (24 regs in flight) and sincos hoisted before it.
// ---------------------------------------------------------------------------

#define NROWS (32768 * 8)   // N_SAMPLES * N_MESH
#define VROWS 50001         // N_VERTS + 1
#define BM 64               // rows per block
#define NW 8                // waves per block

typedef unsigned short u16;
typedef unsigned int u32;
typedef __attribute__((ext_vector_type(8))) short s16x8;   // 8 bf16 bit-patterns
typedef __attribute__((ext_vector_type(4))) float f32x4;

#define MFMA(a, b, c) __builtin_amdgcn_mfma_f32_16x16x32_bf16(a, b, c, 0, 0, 0)

// ---- workspace layout (float offsets) ----
#define WF_OFF 0            // folded view layer0 weights, 64x256 fp32 (k-major)
#define BL0_OFF 16384       // folded view layer0 bias, 256
#define AEFF_OFF 16640      // alpha_W1@alpha_W2, 256
#define CEFFT_OFF 16896     // (color_W1@color_W2)^T, [3][512] (cols 0-255: v, 256-511: ve)
#define BA_OFF 18432        // folded alpha bias scalar
#define BC_OFF 18433        // folded color bias, 3
#define PK_FLOAT_OFF 18560  // packed-weight region starts here (16B aligned)
// ---- packed region (u16 offsets relative to pk base) ----
#define L0H 0               // view fold layer (64x256)  hi
#define L0L 16384
#define L1H 32768           // view_W[1] (256x256)
#define L1L 98304
#define L2H 163840          // vert_W[0]
#define L2L 229376
#define L3H 294912          // vert_W[1]
#define L3L 360448
#define L4H 425984          // We_c^T (color ve-head, 16(3)x256)
#define L4L 430080
// pk total: 434176 u16

__device__ __forceinline__ u16 btrunc(float x) { return (u16)(__float_as_uint(x) >> 16); }
__device__ __forceinline__ u16 bround(float x) {
  u32 u = __float_as_uint(x);
  u += 0x7fff + ((u >> 16) & 1);
  return (u16)(u >> 16);
}

// ---------------------------------------------------------------------------
// prep: fold weights (fp32) into workspace
// ---------------------------------------------------------------------------
__global__ void mc_prep(const float* w_proj, const float* b_proj, const float* view_W,
                        const float* view_b, const float* alpha_W1, const float* alpha_b1,
                        const float* alpha_W2, const float* alpha_b2, const float* color_W1,
                        const float* color_b1, const float* color_W2, const float* color_b2,
                        float* ws) {
  int bid = blockIdx.x, tid = threadIdx.x;
  if (bid < 64) {
    // Wfold[k][n] = sum_j w_proj[k][j] * view_W0[j][n]   (k>=36 -> 0 padding)
    int k = bid, n = tid;
    float s = 0.f;
    if (k < 36)
      for (int j = 0; j < 256; ++j) s = fmaf(w_proj[k * 256 + j], view_W[j * 256 + n], s);
    ws[WF_OFF + k * 256 + n] = s;
  } else if (bid == 64) {
    int n = tid;
    float s = view_b[n];  // view_b[0][n]
    for (int j = 0; j < 256; ++j) s = fmaf(b_proj[j], view_W[j * 256 + n], s);
    ws[BL0_OFF + n] = s;
  } else if (bid == 65) {
    int k = tid;
    float s = 0.f;
    for (int j = 0; j < 256; ++j) s = fmaf(alpha_W1[k * 256 + j], alpha_W2[j], s);
    ws[AEFF_OFF + k] = s;
    if (tid == 0) {
      float b = alpha_b2[0];
      for (int j = 0; j < 256; ++j) b = fmaf(alpha_b1[j], alpha_W2[j], b);
      ws[BA_OFF] = b;
    }
  } else {
    int kk = (bid - 66) * 256 + tid;  // 0..511
    for (int c = 0; c < 3; ++c) {
      float s = 0.f;
      for (int j = 0; j < 512; ++j) s = fmaf(color_W1[kk * 512 + j], color_W2[j * 3 + c], s);
      ws[CEFFT_OFF + c * 512 + kk] = s;  // transposed: [3][512]
    }
    if (bid == 66 && tid == 0) {
      for (int c = 0; c < 3; ++c) {
        float s = color_b2[c];
        for (int j = 0; j < 512; ++j) s = fmaf(color_b1[j], color_W2[j * 3 + c], s);
        ws[BC_OFF + c] = s;
      }
    }
  }
}

// ---------------------------------------------------------------------------
// pack: weights -> hi/lo bf16 A-fragment order (W^T tiles)
// fragment elem (at, ks, lane, j) <- W[ks*32 + (lane>>4)*8 + j][at*16 + (lane&15)]
// ---------------------------------------------------------------------------
__global__ void mc_pack(const float* view_W, const float* vert_W, const float* ws_f, u16* pk) {
  int e = blockIdx.x * 256 + threadIdx.x;  // 0..217087 (exact: 848*256)
  float x;
  int offh, offl, le;
  if (e < 212992) {
    const float* src;
    int KS;
    if (e < 16384) {
      src = ws_f + WF_OFF; KS = 2; offh = L0H; offl = L0L; le = e;
    } else if (e < 81920) {
      src = view_W + 65536; KS = 8; offh = L1H; offl = L1L; le = e - 16384;
    } else if (e < 147456) {
      src = vert_W; KS = 8; offh = L2H; offl = L2L; le = e - 81920;
    } else {
      src = vert_W + 65536; KS = 8; offh = L3H; offl = L3L; le = e - 147456;
    }
    int j = le & 7, lane = (le >> 3) & 63, rest = le >> 9;
    int ks = rest % KS, at = rest / KS;
    int k = ks * 32 + ((lane >> 4) << 3) + j;
    int n = at * 16 + (lane & 15);
    x = src[k * 256 + n];
  } else {
    // L4: We_c^T — A rows = color c (pad to 16), k = ve channel
    le = e - 212992;  // 0..4095
    offh = L4H; offl = L4L;
    int j = le & 7, lane = (le >> 3) & 63, ks = le >> 9;
    int k = ks * 32 + ((lane >> 4) << 3) + j;
    int c = lane & 15;
    x = (c < 3) ? ws_f[CEFFT_OFF + c * 512 + 256 + k] : 0.f;
  }
  u16 h = btrunc(x);
  float r = x - __uint_as_float(((u32)h) << 16);
  pk[offh + le] = h;
  pk[offl + le] = btrunc(r);
}

// ---------------------------------------------------------------------------
// GEMM core (swapped): Z^T = W^T(256xK) @ X^T(Kx64).
// A tiles (n) from pk (each wave owns 2 of 16 n-tiles); B fragments (sample
// rows, rt=0..3) from LDS.
// acc[atl][rt]: lane holds D[n = (wid*2+atl)*16+(lane>>4)*4+reg][row = rt*16+(lane&15)].
// EXTRA: phase-2 color-ve tile, ks slice == wid.
// ---------------------------------------------------------------------------
template <int KS, int AS, bool EXTRA, bool BLO>
__device__ __forceinline__ void run_gemm(const u16* Bh, const u16* Bl, const u16* pk,
                                         int offh, int offl, int wid, int lane,
                                         f32x4 (&acc)[2][4], f32x4* accx) {
#pragma unroll
  for (int ks = 0; ks < KS; ++ks) {
    s16x8 b_h[4], b_l[4];
#pragma unroll
    for (int rt = 0; rt < 4; ++rt) {
      int row = rt * 16 + (lane & 15);
      u32 byte = (u32)(row * AS + ks * 64 + ((lane >> 4) << 4));
      byte ^= ((u32)(row & 7) << 4);
      b_h[rt] = *(const s16x8*)((const char*)Bh + byte);
      if (BLO) b_l[rt] = *(const s16x8*)((const char*)Bl + byte);
    }
#pragma unroll
    for (int atl = 0; atl < 2; ++atl) {
      int at = wid * 2 + atl;
      size_t fidx = ((size_t)(at * KS + ks) * 64 + lane) * 8;
      s16x8 a_h = *(const s16x8*)(pk + offh + fidx);
      s16x8 a_l = *(const s16x8*)(pk + offl + fidx);
#pragma unroll
      for (int rt = 0; rt < 4; ++rt) {
        acc[atl][rt] = MFMA(a_h, b_h[rt], acc[atl][rt]);
        if (BLO) acc[atl][rt] = MFMA(a_h, b_l[rt], acc[atl][rt]);
        acc[atl][rt] = MFMA(a_l, b_h[rt], acc[atl][rt]);
      }
    }
    if (EXTRA) {
      if (ks == wid) {  // wave-uniform: each wave handles one ks slice
        size_t fx = ((size_t)ks * 64 + lane) * 8;
        s16x8 ax_h = *(const s16x8*)(pk + L4H + fx);
        s16x8 ax_l = *(const s16x8*)(pk + L4L + fx);
#pragma unroll
        for (int rt = 0; rt < 4; ++rt) {
          accx[rt] = MFMA(ax_h, b_h[rt], accx[rt]);
          if (BLO) accx[rt] = MFMA(ax_h, b_l[rt], accx[rt]);
          accx[rt] = MFMA(ax_l, b_h[rt], accx[rt]);
        }
      }
    }
  }
}

__device__ __forceinline__ void zero_acc(f32x4 (&acc)[2][4]) {
#pragma unroll
  for (int a = 0; a < 2; ++a)
#pragma unroll
    for (int r = 0; r < 4; ++r) acc[a][r] = (f32x4){0.f, 0.f, 0.f, 0.f};
}

// relu(acc + bias) -> LDS hi/lo, vectorized ushort4 per (atl, rt).
__device__ __forceinline__ void store_relu(const f32x4 (&acc)[2][4], const float* bias,
                                           u16* Oh, u16* Ol, int wid, int lane) {
  const int lg = (lane >> 4) << 2;
#pragma unroll
  for (int atl = 0; atl < 2; ++atl) {
    int nb = (wid * 2 + atl) * 16 + lg;
    f32x4 bv = *(const f32x4*)(bias + nb);
#pragma unroll
    for (int rt = 0; rt < 4; ++rt) {
      int row = rt * 16 + (lane & 15);
      u32 byte = (u32)(row * 512 + nb * 2);
      byte ^= ((u32)(row & 7) << 4);
      float v0 = acc[atl][rt][0] + bv[0]; v0 = v0 > 0.f ? v0 : 0.f;
      float v1 = acc[atl][rt][1] + bv[1]; v1 = v1 > 0.f ? v1 : 0.f;
      float v2 = acc[atl][rt][2] + bv[2]; v2 = v2 > 0.f ? v2 : 0.f;
      float v3 = acc[atl][rt][3] + bv[3]; v3 = v3 > 0.f ? v3 : 0.f;
      ushort4 h, l;
      float r;
      h.x = btrunc(v0); r = v0 - __uint_as_float(((u32)h.x) << 16); l.x = btrunc(r);
      h.y = btrunc(v1); r = v1 - __uint_as_float(((u32)h.y) << 16); l.y = btrunc(r);
      h.z = btrunc(v2); r = v2 - __uint_as_float(((u32)h.z) << 16); l.z = btrunc(r);
      h.w = btrunc(v3); r = v3 - __uint_as_float(((u32)h.w) << 16); l.w = btrunc(r);
      *(ushort4*)((char*)Oh + byte) = h;
      *(ushort4*)((char*)Ol + byte) = l;
    }
  }
}

// ---------------------------------------------------------------------------
// main kernel: 512 threads (8 waves), 64 rows/block, 2 blocks/CU
// ---------------------------------------------------------------------------
__global__ __launch_bounds__(512, 4) void mc_main(const int* __restrict__ verts,
                                                  const float* __restrict__ barys,
                                                  const float* __restrict__ views,
                                                  const float* __restrict__ emb_tables,
                                                  const float* __restrict__ view_b,
                                                  const float* __restrict__ vert_b,
                                                  const float* __restrict__ ws_f,
                                                  const u16* __restrict__ pk,
                                                  float* __restrict__ out) {
  __shared__ u16 ACTh[BM * 256], ACTl[BM * 256];  // in-place activations (64 KB)
  __shared__ u16 Eh[BM * 64];                     // sincos embedding, hi only (8 KB)
  __shared__ float cpart[BM * 4];                 // [row][c0..2=color, 3=alpha] (1 KB)

  const int tid = threadIdx.x, lane = tid & 63, wid = tid >> 6;
  const int rbase = blockIdx.x * BM;

  // zero head-partial accumulators (ds_add targets)
  if (tid < BM * 4) cpart[tid] = 0.f;

  // ---------- Phase 1b: sincos embedding -> E (hi only, padded to 64 cols) ----------
  {
    const int row = tid >> 3, slot = tid & 7;
    const int R = rbase + row;
    if (slot < 6) {
      float f = (float)(1 << slot);
#pragma unroll
      for (int d = 0; d < 3; ++d) {
        float x = views[R * 3 + d] * f;
        float s, c;
        sincosf(x, &s, &c);
        u32 b1 = ((u32)(row * 128 + (slot * 6 + d) * 2)) ^ ((u32)(row & 7) << 4);
        u32 b2 = ((u32)(row * 128 + (slot * 6 + 3 + d) * 2)) ^ ((u32)(row & 7) << 4);
        *(u16*)((char*)Eh + b1) = bround(s);
        *(u16*)((char*)Eh + b2) = bround(c);
      }
    } else {
      int c0 = 36 + (slot - 6) * 14;
      for (int c = c0; c < c0 + 14; ++c) {
        u32 b = ((u32)(row * 128 + c * 2)) ^ ((u32)(row & 7) << 4);
        *(u16*)((char*)Eh + b) = 0;
      }
    }
  }

  // ---------- Phase 1: gather + renorm + bary sum -> ACT (pair-pipelined) ----------
  for (int p = 0; p < 4; ++p) {
    const int row0 = wid * 8 + p * 2;
    float4 val[2][3];
    float bw[2][3];
#pragma unroll
    for (int r = 0; r < 2; ++r) {
      const int R = rbase + row0 + r;
      const int m = R & 7;  // mesh id (R = sample*8 + mesh)
#pragma unroll
      for (int v = 0; v < 3; ++v) {
        int idx = verts[R * 3 + v] + 1;
        bw[r][v] = barys[R * 3 + v];
        val[r][v] = ((const float4*)(emb_tables + ((size_t)m * VROWS + idx) * 256))[lane];
      }
    }
    float ss[2][3];
#pragma unroll
    for (int r = 0; r < 2; ++r)
#pragma unroll
      for (int v = 0; v < 3; ++v)
        ss[r][v] = fmaf(val[r][v].x, val[r][v].x,
                   fmaf(val[r][v].y, val[r][v].y,
                   fmaf(val[r][v].z, val[r][v].z, val[r][v].w * val[r][v].w)));
#pragma unroll
    for (int sh = 1; sh < 64; sh <<= 1) {
#pragma unroll
      for (int r = 0; r < 2; ++r)
#pragma unroll
        for (int v = 0; v < 3; ++v) ss[r][v] += __shfl_xor(ss[r][v], sh);
    }
#pragma unroll
    for (int r = 0; r < 2; ++r) {
      float ax = 0.f, ay = 0.f, az = 0.f, aw = 0.f;
#pragma unroll
      for (int v = 0; v < 3; ++v) {
        float norm = sqrtf(ss[r][v]);
        float scale = norm > 1.f ? 1.f / norm : 1.f;
        float wbs = bw[r][v] * scale;
        ax = fmaf(wbs, val[r][v].x, ax);
        ay = fmaf(wbs, val[r][v].y, ay);
        az = fmaf(wbs, val[r][v].z, az);
        aw = fmaf(wbs, val[r][v].w, aw);
      }
      const int row = row0 + r;
      u32 byte = (u32)(row * 512 + lane * 8);
      byte ^= ((u32)(row & 7) << 4);
      ushort4 h, l;
      float rr;
      h.x = btrunc(ax); rr = ax - __uint_as_float(((u32)h.x) << 16); l.x = btrunc(rr);
      h.y = btrunc(ay); rr = ay - __uint_as_float(((u32)h.y) << 16); l.y = btrunc(rr);
      h.z = btrunc(az); rr = az - __uint_as_float(((u32)h.z) << 16); l.z = btrunc(rr);
      h.w = btrunc(aw); rr = aw - __uint_as_float(((u32)h.w) << 16); l.w = btrunc(rr);
      *(ushort4*)((char*)ACTh + byte) = h;
      *(ushort4*)((char*)ACTl + byte) = l;
    }
  }
  __syncthreads();  // S1: ACT(ve), E, cpart-zero ready

  // ---------- Phase 2: h1 = relu(ve @ vert_W0 + b); color-ve extra tile ----------
  {
    f32x4 acc[2][4], accx[4];
    zero_acc(acc);
#pragma unroll
    for (int rt = 0; rt < 4; ++rt) accx[rt] = (f32x4){0.f, 0.f, 0.f, 0.f};
    run_gemm<8, 512, true, true>(ACTh, ACTl, pk, L2H, L2L, wid, lane, acc, accx);
    // color-ve partials: lanes 0-15 hold D[c=reg][row=rt*16+lane]
    if (lane < 16) {
#pragma unroll
      for (int rt = 0; rt < 4; ++rt)
#pragma unroll
        for (int c = 0; c < 3; ++c)
          atomicAdd(&cpart[(rt * 16 + lane) * 4 + c], accx[rt][c]);
    }
    __syncthreads();  // S2: all ACT reads done
    store_relu(acc, vert_b, ACTh, ACTl, wid, lane);
  }
  __syncthreads();  // S3: h1 ready

  // ---------- Phase 3: h2 = relu(h1 @ vert_W1 + b); alpha = relu(h2) . a_eff ----------
  {
    f32x4 acc[2][4];
    zero_acc(acc);
    run_gemm<8, 512, false, true>(ACTh, ACTl, pk, L3H, L3L, wid, lane, acc, nullptr);
    const int lg = (lane >> 4) << 2;
    float s[4] = {0.f, 0.f, 0.f, 0.f};
#pragma unroll
    for (int atl = 0; atl < 2; ++atl) {
      int nb = (wid * 2 + atl) * 16 + lg;
      f32x4 bv = *(const f32x4*)(vert_b + 256 + nb);
      f32x4 av = *(const f32x4*)(ws_f + AEFF_OFF + nb);
#pragma unroll
      for (int rt = 0; rt < 4; ++rt)
#pragma unroll
        for (int reg = 0; reg < 4; ++reg) {
          float v = acc[atl][rt][reg] + bv[reg];
          v = v > 0.f ? v : 0.f;
          s[rt] = fmaf(v, av[reg], s[rt]);
        }
    }
#pragma unroll
    for (int rt = 0; rt < 4; ++rt) {
      s[rt] += __shfl_xor(s[rt], 16);
      s[rt] += __shfl_xor(s[rt], 32);
    }
    if (lane < 16) {
#pragma unroll
      for (int rt = 0; rt < 4; ++rt) atomicAdd(&cpart[(rt * 16 + lane) * 4 + 3], s[rt]);
    }
  }
  __syncthreads();  // S4: all ACT(h1) reads done

  // ---------- Phase 4: v1 = relu(E @ Wfold + bL0) -> ACT ----------
  {
    f32x4 acc[2][4];
    zero_acc(acc);
    run_gemm<2, 128, false, false>(Eh, Eh, pk, L0H, L0L, wid, lane, acc, nullptr);
    store_relu(acc, ws_f + BL0_OFF, ACTh, ACTl, wid, lane);
  }
  __syncthreads();  // S5: v1 ready

  // ---------- Phase 5: v2 = relu(v1 @ view_W1 + b); color += relu(v2) . Wv_c ----------
  {
    f32x4 acc[2][4];
    zero_acc(acc);
    run_gemm<8, 512, false, true>(ACTh, ACTl, pk, L1H, L1L, wid, lane, acc, nullptr);
    const int lg = (lane >> 4) << 2;
    float s[4][3];
#pragma unroll
    for (int rt = 0; rt < 4; ++rt)
#pragma unroll
      for (int c = 0; c < 3; ++c) s[rt][c] = 0.f;
#pragma unroll
    for (int atl = 0; atl < 2; ++atl) {
      int nb = (wid * 2 + atl) * 16 + lg;
      f32x4 bv = *(const f32x4*)(view_b + 256 + nb);
      f32x4 w0 = *(const f32x4*)(ws_f + CEFFT_OFF + 0 * 512 + nb);
      f32x4 w1 = *(const f32x4*)(ws_f + CEFFT_OFF + 1 * 512 + nb);
      f32x4 w2 = *(const f32x4*)(ws_f + CEFFT_OFF + 2 * 512 + nb);
#pragma unroll
      for (int rt = 0; rt < 4; ++rt)
#pragma unroll
        for (int reg = 0; reg < 4; ++reg) {
          float v = acc[atl][rt][reg] + bv[reg];
          v = v > 0.f ? v : 0.f;
          s[rt][0] = fmaf(v, w0[reg], s[rt][0]);
          s[rt][1] = fmaf(v, w1[reg], s[rt][1]);
          s[rt][2] = fmaf(v, w2[reg], s[rt][2]);
        }
    }
#pragma unroll
    for (int rt = 0; rt < 4; ++rt)
#pragma unroll
      for (int c = 0; c < 3; ++c) {
        s[rt][c] += __shfl_xor(s[rt][c], 16);
        s[rt][c] += __shfl_xor(s[rt][c], 32);
      }
    if (lane < 16) {
#pragma unroll
      for (int rt = 0; rt < 4; ++rt)
#pragma unroll
        for (int c = 0; c < 3; ++c)
          atomicAdd(&cpart[(rt * 16 + lane) * 4 + c], s[rt][c]);
    }
  }
  __syncthreads();  // S6: partials complete

  // ---------- Phase 6: writeout (N, M, 4) = [colors, alpha] ----------
  if (tid < BM * 4) {
    int c = tid & 3;
    float v = cpart[tid] + (c < 3 ? ws_f[BC_OFF + c] : ws_f[BA_OFF]);
    out[(size_t)rbase * 4 + tid] = v;
  }
}

// ---------------------------------------------------------------------------
extern "C" void kernel_launch(void* const* d_in, const int* in_sizes, int n_in, void* d_out,
                              int out_size, void* d_ws, size_t ws_size, hipStream_t stream) {
  (void)in_sizes; (void)n_in; (void)out_size; (void)ws_size;
  const int* verts = (const int*)d_in[0];
  const float* barys = (const float*)d_in[1];
  const float* views = (const float*)d_in[2];
  const float* emb_tables = (const float*)d_in[3];
  const float* w_proj = (const float*)d_in[4];
  const float* b_proj = (const float*)d_in[5];
  const float* view_W = (const float*)d_in[6];
  const float* view_b = (const float*)d_in[7];
  const float* vert_W = (const float*)d_in[8];
  const float* vert_b = (const float*)d_in[9];
  const float* alpha_W1 = (const float*)d_in[10];
  const float* alpha_b1 = (const float*)d_in[11];
  const float* alpha_W2 = (const float*)d_in[12];
  const float* alpha_b2 = (const float*)d_in[13];
  const float* color_W1 = (const float*)d_in[14];
  const float* color_b1 = (const float*)d_in[15];
  const float* color_W2 = (const float*)d_in[16];
  const float* color_b2 = (const float*)d_in[17];

  float* ws_f = (float*)d_ws;
  u16* pk = (u16*)(ws_f + PK_FLOAT_OFF);

  mc_prep<<<dim3(68), dim3(256), 0, stream>>>(w_proj, b_proj, view_W, view_b, alpha_W1,
                                              alpha_b1, alpha_W2, alpha_b2, color_W1, color_b1,
                                              color_W2, color_b2, ws_f);
  mc_pack<<<dim3(848), dim3(256), 0, stream>>>(view_W, vert_W, ws_f, pk);
  mc_main<<<dim3(NROWS / BM), dim3(512), 0, stream>>>(verts, barys, views, emb_tables, view_b,
                                                      vert_b, ws_f, pk, (float*)d_out);
}

// Round 7
// 909.676 us; speedup vs baseline: 1.1407x; 1.1407x over previous
//
#include <hip/hip_runtime.h>
#include <math.h>

// ---------------------------------------------------------------------------
// MeshCaster on MI355X — round 7.
// r5/r6 (588/560us) lost to r4 (521us) via scratch spill (WRITE_SIZE 241MB):
// AGPR acc shares the gfx950 unified file; launch_bounds(512,4) caps 128/lane
// and the fully-unrolled gemm held B[4]x2 + acc + accx over the cap.
// r7: per-rt transient B fragments, unroll-2 ks loop, color-ve tile in a
// separate scoped post-pass. Target: zero spill at 2 blocks/CU, BM=64 kept.
// ---------------------------------------------------------------------------

#define NROWS (32768 * 8)   // N_SAMPLES * N_MESH
#define VROWS 50001         // N_VERTS + 1
#define BM 64               // rows per block
#define NW 8                // waves per block

typedef unsigned short u16;
typedef unsigned int u32;
typedef __attribute__((ext_vector_type(8))) short s16x8;   // 8 bf16 bit-patterns
typedef __attribute__((ext_vector_type(4))) float f32x4;

#define MFMA(a, b, c) __builtin_amdgcn_mfma_f32_16x16x32_bf16(a, b, c, 0, 0, 0)

// ---- workspace layout (float offsets) ----
#define WF_OFF 0            // folded view layer0 weights, 64x256 fp32 (k-major)
#define BL0_OFF 16384       // folded view layer0 bias, 256
#define AEFF_OFF 16640      // alpha_W1@alpha_W2, 256
#define CEFFT_OFF 16896     // (color_W1@color_W2)^T, [3][512] (cols 0-255: v, 256-511: ve)
#define BA_OFF 18432        // folded alpha bias scalar
#define BC_OFF 18433        // folded color bias, 3
#define PK_FLOAT_OFF 18560  // packed-weight region starts here (16B aligned)
// ---- packed region (u16 offsets relative to pk base) ----
#define L0H 0               // view fold layer (64x256)  hi
#define L0L 16384
#define L1H 32768           // view_W[1] (256x256)
#define L1L 98304
#define L2H 163840          // vert_W[0]
#define L2L 229376
#define L3H 294912          // vert_W[1]
#define L3L 360448
#define L4H 425984          // We_c^T (color ve-head, 16(3)x256)
#define L4L 430080
// pk total: 434176 u16

__device__ __forceinline__ u16 btrunc(float x) { return (u16)(__float_as_uint(x) >> 16); }
__device__ __forceinline__ u16 bround(float x) {
  u32 u = __float_as_uint(x);
  u += 0x7fff + ((u >> 16) & 1);
  return (u16)(u >> 16);
}

// ---------------------------------------------------------------------------
// prep: fold weights (fp32) into workspace
// ---------------------------------------------------------------------------
__global__ void mc_prep(const float* w_proj, const float* b_proj, const float* view_W,
                        const float* view_b, const float* alpha_W1, const float* alpha_b1,
                        const float* alpha_W2, const float* alpha_b2, const float* color_W1,
                        const float* color_b1, const float* color_W2, const float* color_b2,
                        float* ws) {
  int bid = blockIdx.x, tid = threadIdx.x;
  if (bid < 64) {
    // Wfold[k][n] = sum_j w_proj[k][j] * view_W0[j][n]   (k>=36 -> 0 padding)
    int k = bid, n = tid;
    float s = 0.f;
    if (k < 36)
      for (int j = 0; j < 256; ++j) s = fmaf(w_proj[k * 256 + j], view_W[j * 256 + n], s);
    ws[WF_OFF + k * 256 + n] = s;
  } else if (bid == 64) {
    int n = tid;
    float s = view_b[n];  // view_b[0][n]
    for (int j = 0; j < 256; ++j) s = fmaf(b_proj[j], view_W[j * 256 + n], s);
    ws[BL0_OFF + n] = s;
  } else if (bid == 65) {
    int k = tid;
    float s = 0.f;
    for (int j = 0; j < 256; ++j) s = fmaf(alpha_W1[k * 256 + j], alpha_W2[j], s);
    ws[AEFF_OFF + k] = s;
    if (tid == 0) {
      float b = alpha_b2[0];
      for (int j = 0; j < 256; ++j) b = fmaf(alpha_b1[j], alpha_W2[j], b);
      ws[BA_OFF] = b;
    }
  } else {
    int kk = (bid - 66) * 256 + tid;  // 0..511
    for (int c = 0; c < 3; ++c) {
      float s = 0.f;
      for (int j = 0; j < 512; ++j) s = fmaf(color_W1[kk * 512 + j], color_W2[j * 3 + c], s);
      ws[CEFFT_OFF + c * 512 + kk] = s;  // transposed: [3][512]
    }
    if (bid == 66 && tid == 0) {
      for (int c = 0; c < 3; ++c) {
        float s = color_b2[c];
        for (int j = 0; j < 512; ++j) s = fmaf(color_b1[j], color_W2[j * 3 + c], s);
        ws[BC_OFF + c] = s;
      }
    }
  }
}

// ---------------------------------------------------------------------------
// pack: weights -> hi/lo bf16 A-fragment order (W^T tiles)
// fragment elem (at, ks, lane, j) <- W[ks*32 + (lane>>4)*8 + j][at*16 + (lane&15)]
// ---------------------------------------------------------------------------
__global__ void mc_pack(const float* view_W, const float* vert_W, const float* ws_f, u16* pk) {
  int e = blockIdx.x * 256 + threadIdx.x;  // 0..217087 (exact: 848*256)
  float x;
  int offh, offl, le;
  if (e < 212992) {
    const float* src;
    int KS;
    if (e < 16384) {
      src = ws_f + WF_OFF; KS = 2; offh = L0H; offl = L0L; le = e;
    } else if (e < 81920) {
      src = view_W + 65536; KS = 8; offh = L1H; offl = L1L; le = e - 16384;
    } else if (e < 147456) {
      src = vert_W; KS = 8; offh = L2H; offl = L2L; le = e - 81920;
    } else {
      src = vert_W + 65536; KS = 8; offh = L3H; offl = L3L; le = e - 147456;
    }
    int j = le & 7, lane = (le >> 3) & 63, rest = le >> 9;
    int ks = rest % KS, at = rest / KS;
    int k = ks * 32 + ((lane >> 4) << 3) + j;
    int n = at * 16 + (lane & 15);
    x = src[k * 256 + n];
  } else {
    // L4: We_c^T — A rows = color c (pad to 16), k = ve channel
    le = e - 212992;  // 0..4095
    offh = L4H; offl = L4L;
    int j = le & 7, lane = (le >> 3) & 63, ks = le >> 9;
    int k = ks * 32 + ((lane >> 4) << 3) + j;
    int c = lane & 15;
    x = (c < 3) ? ws_f[CEFFT_OFF + c * 512 + 256 + k] : 0.f;
  }
  u16 h = btrunc(x);
  float r = x - __uint_as_float(((u32)h) << 16);
  pk[offh + le] = h;
  pk[offl + le] = btrunc(r);
}

// ---------------------------------------------------------------------------
// GEMM core (swapped): Z^T = W^T(256xK) @ X^T(Kx64).
// Low-pressure form: per ks, hold 4 A fragments (16 regs); B fragments are
// transient per rt (8 regs, 6 MFMAs, dead). unroll-2 keeps live ranges short.
// acc[atl][rt]: lane holds D[n=(wid*2+atl)*16+(lane>>4)*4+reg][row=rt*16+(lane&15)].
// ---------------------------------------------------------------------------
template <int KS, int AS, bool BLO>
__device__ __forceinline__ void run_gemm(const u16* Bh, const u16* Bl, const u16* pk,
                                         int offh, int offl, int wid, int lane,
                                         f32x4 (&acc)[2][4]) {
#pragma unroll 2
  for (int ks = 0; ks < KS; ++ks) {
    s16x8 a_h[2], a_l[2];
#pragma unroll
    for (int atl = 0; atl < 2; ++atl) {
      int at = wid * 2 + atl;
      size_t fidx = ((size_t)(at * KS + ks) * 64 + lane) * 8;
      a_h[atl] = *(const s16x8*)(pk + offh + fidx);
      a_l[atl] = *(const s16x8*)(pk + offl + fidx);
    }
#pragma unroll
    for (int rt = 0; rt < 4; ++rt) {
      int row = rt * 16 + (lane & 15);
      u32 byte = (u32)(row * AS + ks * 64 + ((lane >> 4) << 4));
      byte ^= ((u32)(row & 7) << 4);
      s16x8 b_h = *(const s16x8*)((const char*)Bh + byte);
      acc[0][rt] = MFMA(a_h[0], b_h, acc[0][rt]);
      acc[1][rt] = MFMA(a_h[1], b_h, acc[1][rt]);
      acc[0][rt] = MFMA(a_l[0], b_h, acc[0][rt]);
      acc[1][rt] = MFMA(a_l[1], b_h, acc[1][rt]);
      if (BLO) {
        s16x8 b_l = *(const s16x8*)((const char*)Bl + byte);
        acc[0][rt] = MFMA(a_h[0], b_l, acc[0][rt]);
        acc[1][rt] = MFMA(a_h[1], b_l, acc[1][rt]);
      }
    }
  }
}

__device__ __forceinline__ void zero_acc(f32x4 (&acc)[2][4]) {
#pragma unroll
  for (int a = 0; a < 2; ++a)
#pragma unroll
    for (int r = 0; r < 4; ++r) acc[a][r] = (f32x4){0.f, 0.f, 0.f, 0.f};
}

// relu(acc + bias) -> LDS hi/lo, vectorized ushort4 per (atl, rt).
__device__ __forceinline__ void store_relu(const f32x4 (&acc)[2][4], const float* bias,
                                           u16* Oh, u16* Ol, int wid, int lane) {
  const int lg = (lane >> 4) << 2;
#pragma unroll
  for (int atl = 0; atl < 2; ++atl) {
    int nb = (wid * 2 + atl) * 16 + lg;
    f32x4 bv = *(const f32x4*)(bias + nb);
#pragma unroll
    for (int rt = 0; rt < 4; ++rt) {
      int row = rt * 16 + (lane & 15);
      u32 byte = (u32)(row * 512 + nb * 2);
      byte ^= ((u32)(row & 7) << 4);
      float v0 = acc[atl][rt][0] + bv[0]; v0 = v0 > 0.f ? v0 : 0.f;
      float v1 = acc[atl][rt][1] + bv[1]; v1 = v1 > 0.f ? v1 : 0.f;
      float v2 = acc[atl][rt][2] + bv[2]; v2 = v2 > 0.f ? v2 : 0.f;
      float v3 = acc[atl][rt][3] + bv[3]; v3 = v3 > 0.f ? v3 : 0.f;
      ushort4 h, l;
      float r;
      h.x = btrunc(v0); r = v0 - __uint_as_float(((u32)h.x) << 16); l.x = btrunc(r);
      h.y = btrunc(v1); r = v1 - __uint_as_float(((u32)h.y) << 16); l.y = btrunc(r);
      h.z = btrunc(v2); r = v2 - __uint_as_float(((u32)h.z) << 16); l.z = btrunc(r);
      h.w = btrunc(v3); r = v3 - __uint_as_float(((u32)h.w) << 16); l.w = btrunc(r);
      *(ushort4*)((char*)Oh + byte) = h;
      *(ushort4*)((char*)Ol + byte) = l;
    }
  }
}

// ---------------------------------------------------------------------------
// main kernel: 512 threads (8 waves), 64 rows/block, 2 blocks/CU
// ---------------------------------------------------------------------------
__global__ __launch_bounds__(512, 4) void mc_main(const int* __restrict__ verts,
                                                  const float* __restrict__ barys,
                                                  const float* __restrict__ views,
                                                  const float* __restrict__ emb_tables,
                                                  const float* __restrict__ view_b,
                                                  const float* __restrict__ vert_b,
                                                  const float* __restrict__ ws_f,
                                                  const u16* __restrict__ pk,
                                                  float* __restrict__ out) {
  __shared__ u16 ACTh[BM * 256], ACTl[BM * 256];  // in-place activations (64 KB)
  __shared__ u16 Eh[BM * 64];                     // sincos embedding, hi only (8 KB)
  __shared__ float cpart[BM * 4];                 // [row][c0..2=color, 3=alpha] (1 KB)

  const int tid = threadIdx.x, lane = tid & 63, wid = tid >> 6;
  const int rbase = blockIdx.x * BM;

  // zero head-partial accumulators (ds_add targets)
  if (tid < BM * 4) cpart[tid] = 0.f;

  // ---------- Phase 1b: sincos embedding -> E (hi only, padded to 64 cols) ----------
  {
    const int row = tid >> 3, slot = tid & 7;
    const int R = rbase + row;
    if (slot < 6) {
      float f = (float)(1 << slot);
#pragma unroll
      for (int d = 0; d < 3; ++d) {
        float x = views[R * 3 + d] * f;
        float s, c;
        sincosf(x, &s, &c);
        u32 b1 = ((u32)(row * 128 + (slot * 6 + d) * 2)) ^ ((u32)(row & 7) << 4);
        u32 b2 = ((u32)(row * 128 + (slot * 6 + 3 + d) * 2)) ^ ((u32)(row & 7) << 4);
        *(u16*)((char*)Eh + b1) = bround(s);
        *(u16*)((char*)Eh + b2) = bround(c);
      }
    } else {
      int c0 = 36 + (slot - 6) * 14;
      for (int c = c0; c < c0 + 14; ++c) {
        u32 b = ((u32)(row * 128 + c * 2)) ^ ((u32)(row & 7) << 4);
        *(u16*)((char*)Eh + b) = 0;
      }
    }
  }

  // ---------- Phase 1: gather + renorm + bary sum -> ACT (pair-pipelined) ----------
  for (int p = 0; p < 4; ++p) {
    const int row0 = wid * 8 + p * 2;
    float4 val[2][3];
    float bw[2][3];
#pragma unroll
    for (int r = 0; r < 2; ++r) {
      const int R = rbase + row0 + r;
      const int m = R & 7;  // mesh id (R = sample*8 + mesh)
#pragma unroll
      for (int v = 0; v < 3; ++v) {
        int idx = verts[R * 3 + v] + 1;
        bw[r][v] = barys[R * 3 + v];
        val[r][v] = ((const float4*)(emb_tables + ((size_t)m * VROWS + idx) * 256))[lane];
      }
    }
    float ss[2][3];
#pragma unroll
    for (int r = 0; r < 2; ++r)
#pragma unroll
      for (int v = 0; v < 3; ++v)
        ss[r][v] = fmaf(val[r][v].x, val[r][v].x,
                   fmaf(val[r][v].y, val[r][v].y,
                   fmaf(val[r][v].z, val[r][v].z, val[r][v].w * val[r][v].w)));
#pragma unroll
    for (int sh = 1; sh < 64; sh <<= 1) {
#pragma unroll
      for (int r = 0; r < 2; ++r)
#pragma unroll
        for (int v = 0; v < 3; ++v) ss[r][v] += __shfl_xor(ss[r][v], sh);
    }
#pragma unroll
    for (int r = 0; r < 2; ++r) {
      float ax = 0.f, ay = 0.f, az = 0.f, aw = 0.f;
#pragma unroll
      for (int v = 0; v < 3; ++v) {
        float norm = sqrtf(ss[r][v]);
        float scale = norm > 1.f ? 1.f / norm : 1.f;
        float wbs = bw[r][v] * scale;
        ax = fmaf(wbs, val[r][v].x, ax);
        ay = fmaf(wbs, val[r][v].y, ay);
        az = fmaf(wbs, val[r][v].z, az);
        aw = fmaf(wbs, val[r][v].w, aw);
      }
      const int row = row0 + r;
      u32 byte = (u32)(row * 512 + lane * 8);
      byte ^= ((u32)(row & 7) << 4);
      ushort4 h, l;
      float rr;
      h.x = btrunc(ax); rr = ax - __uint_as_float(((u32)h.x) << 16); l.x = btrunc(rr);
      h.y = btrunc(ay); rr = ay - __uint_as_float(((u32)h.y) << 16); l.y = btrunc(rr);
      h.z = btrunc(az); rr = az - __uint_as_float(((u32)h.z) << 16); l.z = btrunc(rr);
      h.w = btrunc(aw); rr = aw - __uint_as_float(((u32)h.w) << 16); l.w = btrunc(rr);
      *(ushort4*)((char*)ACTh + byte) = h;
      *(ushort4*)((char*)ACTl + byte) = l;
    }
  }
  __syncthreads();  // S1: ACT(ve), E, cpart-zero ready

  // ---------- Phase 2: h1 = relu(ve @ vert_W0 + b); color-ve post-pass ----------
  {
    f32x4 acc[2][4];
    zero_acc(acc);
    run_gemm<8, 512, true>(ACTh, ACTl, pk, L2H, L2L, wid, lane, acc);
    // color-ve tile: this wave's ks slice == wid (scoped accx, 12 MFMAs)
    {
      const int ks = wid;
      size_t fx = ((size_t)ks * 64 + lane) * 8;
      s16x8 ax_h = *(const s16x8*)(pk + L4H + fx);
      s16x8 ax_l = *(const s16x8*)(pk + L4L + fx);
      f32x4 accx[4];
#pragma unroll
      for (int rt = 0; rt < 4; ++rt) accx[rt] = (f32x4){0.f, 0.f, 0.f, 0.f};
#pragma unroll
      for (int rt = 0; rt < 4; ++rt) {
        int row = rt * 16 + (lane & 15);
        u32 byte = (u32)(row * 512 + ks * 64 + ((lane >> 4) << 4));
        byte ^= ((u32)(row & 7) << 4);
        s16x8 b_h = *(const s16x8*)((const char*)ACTh + byte);
        s16x8 b_l = *(const s16x8*)((const char*)ACTl + byte);
        accx[rt] = MFMA(ax_h, b_h, accx[rt]);
        accx[rt] = MFMA(ax_h, b_l, accx[rt]);
        accx[rt] = MFMA(ax_l, b_h, accx[rt]);
      }
      // lanes 0-15 hold D[c=reg][row=rt*16+lane]
      if (lane < 16) {
#pragma unroll
        for (int rt = 0; rt < 4; ++rt)
#pragma unroll
          for (int c = 0; c < 3; ++c)
            atomicAdd(&cpart[(rt * 16 + lane) * 4 + c], accx[rt][c]);
      }
    }
    __syncthreads();  // S2: all ACT reads done
    store_relu(acc, vert_b, ACTh, ACTl, wid, lane);
  }
  __syncthreads();  // S3: h1 ready

  // ---------- Phase 3: h2 = relu(h1 @ vert_W1 + b); alpha = relu(h2) . a_eff ----------
  {
    f32x4 acc[2][4];
    zero_acc(acc);
    run_gemm<8, 512, true>(ACTh, ACTl, pk, L3H, L3L, wid, lane, acc);
    const int lg = (lane >> 4) << 2;
    float s[4] = {0.f, 0.f, 0.f, 0.f};
#pragma unroll
    for (int atl = 0; atl < 2; ++atl) {
      int nb = (wid * 2 + atl) * 16 + lg;
      f32x4 bv = *(const f32x4*)(vert_b + 256 + nb);
      f32x4 av = *(const f32x4*)(ws_f + AEFF_OFF + nb);
#pragma unroll
      for (int rt = 0; rt < 4; ++rt)
#pragma unroll
        for (int reg = 0; reg < 4; ++reg) {
          float v = acc[atl][rt][reg] + bv[reg];
          v = v > 0.f ? v : 0.f;
          s[rt] = fmaf(v, av[reg], s[rt]);
        }
    }
#pragma unroll
    for (int rt = 0; rt < 4; ++rt) {
      s[rt] += __shfl_xor(s[rt], 16);
      s[rt] += __shfl_xor(s[rt], 32);
    }
    if (lane < 16) {
#pragma unroll
      for (int rt = 0; rt < 4; ++rt) atomicAdd(&cpart[(rt * 16 + lane) * 4 + 3], s[rt]);
    }
  }
  __syncthreads();  // S4: all ACT(h1) reads done

  // ---------- Phase 4: v1 = relu(E @ Wfold + bL0) -> ACT ----------
  {
    f32x4 acc[2][4];
    zero_acc(acc);
    run_gemm<2, 128, false>(Eh, Eh, pk, L0H, L0L, wid, lane, acc);
    store_relu(acc, ws_f + BL0_OFF, ACTh, ACTl, wid, lane);
  }
  __syncthreads();  // S5: v1 ready

  // ---------- Phase 5: v2 = relu(v1 @ view_W1 + b); color += relu(v2) . Wv_c ----------
  {
    f32x4 acc[2][4];
    zero_acc(acc);
    run_gemm<8, 512, true>(ACTh, ACTl, pk, L1H, L1L, wid, lane, acc);
    const int lg = (lane >> 4) << 2;
    float s[4][3];
#pragma unroll
    for (int rt = 0; rt < 4; ++rt)
#pragma unroll
      for (int c = 0; c < 3; ++c) s[rt][c] = 0.f;
#pragma unroll
    for (int atl = 0; atl < 2; ++atl) {
      int nb = (wid * 2 + atl) * 16 + lg;
      f32x4 bv = *(const f32x4*)(view_b + 256 + nb);
      f32x4 w0 = *(const f32x4*)(ws_f + CEFFT_OFF + 0 * 512 + nb);
      f32x4 w1 = *(const f32x4*)(ws_f + CEFFT_OFF + 1 * 512 + nb);
      f32x4 w2 = *(const f32x4*)(ws_f + CEFFT_OFF + 2 * 512 + nb);
#pragma unroll
      for (int rt = 0; rt < 4; ++rt)
#pragma unroll
        for (int reg = 0; reg < 4; ++reg) {
          float v = acc[atl][rt][reg] + bv[reg];
          v = v > 0.f ? v : 0.f;
          s[rt][0] = fmaf(v, w0[reg], s[rt][0]);
          s[rt][1] = fmaf(v, w1[reg], s[rt][1]);
          s[rt][2] = fmaf(v, w2[reg], s[rt][2]);
        }
    }
#pragma unroll
    for (int rt = 0; rt < 4; ++rt)
#pragma unroll
      for (int c = 0; c < 3; ++c) {
        s[rt][c] += __shfl_xor(s[rt][c], 16);
        s[rt][c] += __shfl_xor(s[rt][c], 32);
      }
    if (lane < 16) {
#pragma unroll
      for (int rt = 0; rt < 4; ++rt)
#pragma unroll
        for (int c = 0; c < 3; ++c)
          atomicAdd(&cpart[(rt * 16 + lane) * 4 + c], s[rt][c]);
    }
  }
  __syncthreads();  // S6: partials complete

  // ---------- Phase 6: writeout (N, M, 4) = [colors, alpha] ----------
  if (tid < BM * 4) {
    int c = tid & 3;
    float v = cpart[tid] + (c < 3 ? ws_f[BC_OFF + c] : ws_f[BA_OFF]);
    out[(size_t)rbase * 4 + tid] = v;
  }
}

// ---------------------------------------------------------------------------
extern "C" void kernel_launch(void* const* d_in, const int* in_sizes, int n_in, void* d_out,
                              int out_size, void* d_ws, size_t ws_size, hipStream_t stream) {
  (void)in_sizes; (void)n_in; (void)out_size; (void)ws_size;
  const int* verts = (const int*)d_in[0];
  const float* barys = (const float*)d_in[1];
  const float* views = (const float*)d_in[2];
  const float* emb_tables = (const float*)d_in[3];
  const float* w_proj = (const float*)d_in[4];
  const float* b_proj = (const float*)d_in[5];
  const float* view_W = (const float*)d_in[6];
  const float* view_b = (const float*)d_in[7];
  const float* vert_W = (const float*)d_in[8];
  const float* vert_b = (const float*)d_in[9];
  const float* alpha_W1 = (const float*)d_in[10];
  const float* alpha_b1 = (const float*)d_in[11];
  const float* alpha_W2 = (const float*)d_in[12];
  const float* alpha_b2 = (const float*)d_in[13];
  const float* color_W1 = (const float*)d_in[14];
  const float* color_b1 = (const float*)d_in[15];
  const float* color_W2 = (const float*)d_in[16];
  const float* color_b2 = (const float*)d_in[17];

  float* ws_f = (float*)d_ws;
  u16* pk = (u16*)(ws_f + PK_FLOAT_OFF);

  mc_prep<<<dim3(68), dim3(256), 0, stream>>>(w_proj, b_proj, view_W, view_b, alpha_W1,
                                              alpha_b1, alpha_W2, alpha_b2, color_W1, color_b1,
                                              color_W2, color_b2, ws_f);
  mc_pack<<<dim3(848), dim3(256), 0, stream>>>(view_W, vert_W, ws_f, pk);
  mc_main<<<dim3(NROWS / BM), dim3(512), 0, stream>>>(verts, barys, views, emb_tables, view_b,
                                                      vert_b, ws_f, pk, (float*)d_out);
}